// Round 12
// baseline (79.674 us; speedup 1.0000x reference)
//
#include <hip/hip_runtime.h>
#include <hip/hip_fp16.h>

#define NCITY 384
#define BATCH 4
#define DIM   128
#define HID   256
#define M_TOT (BATCH * NCITY)   // 1536
#define TR    6                 // rows per block -> 256 blocks == 256 CUs
#define NBLK  (M_TOT / TR)      // 256
#define NTASK (576 + BATCH)     // 576 pair tiles + 4 softmax

// ---------------------------------------------------------------------------
// packed f16 helpers (raw VOP3P; ROCm header __hmax2 broken on gfx950)
// ---------------------------------------------------------------------------
__device__ __forceinline__ unsigned pk_add(unsigned a, unsigned b) {
    unsigned r; asm("v_pk_add_f16 %0, %1, %2" : "=v"(r) : "v"(a), "v"(b)); return r;
}
__device__ __forceinline__ unsigned pk_max0(unsigned a) {
    unsigned r; asm("v_pk_max_f16 %0, %1, %2" : "=v"(r) : "v"(a), "v"(0u)); return r;
}
__device__ __forceinline__ unsigned pk_fma(unsigned a, unsigned b, unsigned c) {
    unsigned r; asm("v_pk_fma_f16 %0, %1, %2, %3" : "=v"(r) : "v"(a), "v"(b), "v"(c)); return r;
}
__device__ __forceinline__ unsigned pack2(float a, float b) {
    union { __half2 h2; unsigned u; } c;
    c.h2 = __float22half2_rn(make_float2(a, b));
    return c.u;
}
__device__ __forceinline__ float sum2(unsigned u) {
    union { unsigned u; __half2 h2; } c; c.u = u;
    return __low2float(c.h2) + __high2float(c.h2);
}
union H8 { float4 f4; unsigned u[4]; };

// ---------------------------------------------------------------------------
// streaming head-chunk GEMM (R11-proven): W[128][256] from global, k-split 4,
// cross-wave reduce through LDS scratch.
// ---------------------------------------------------------------------------
__device__ __forceinline__ void chunk_stream(
    const float* __restrict__ W,
    const float (*emb_s)[DIM], float* scr, int tid, float out6[TR])
{
    const int c4 = tid & 63;
    const int wv = tid >> 6;
    const int k0 = wv * 32;

    float4 acc[TR];
    #pragma unroll
    for (int rr = 0; rr < TR; ++rr) acc[rr] = make_float4(0.f, 0.f, 0.f, 0.f);

    #pragma unroll 2
    for (int kb = 0; kb < 32; kb += 4) {
        float4 ev[TR];
        #pragma unroll
        for (int rr = 0; rr < TR; ++rr)
            ev[rr] = *(const float4*)&emb_s[rr][k0 + kb];
        #pragma unroll
        for (int kk = 0; kk < 4; ++kk) {
            const float4 w4 = *(const float4*)&W[(k0 + kb + kk) * HID + c4 * 4];
            #pragma unroll
            for (int rr = 0; rr < TR; ++rr) {
                const float e = ((const float*)&ev[rr])[kk];
                acc[rr].x = fmaf(e, w4.x, acc[rr].x);
                acc[rr].y = fmaf(e, w4.y, acc[rr].y);
                acc[rr].z = fmaf(e, w4.z, acc[rr].z);
                acc[rr].w = fmaf(e, w4.w, acc[rr].w);
            }
        }
    }
    __syncthreads();
    #pragma unroll
    for (int rr = 0; rr < TR; ++rr)
        *(float4*)&scr[(wv * TR + rr) * HID + c4 * 4] = acc[rr];
    __syncthreads();
    #pragma unroll
    for (int rr = 0; rr < TR; ++rr)
        out6[rr] = scr[(0 * TR + rr) * HID + tid] + scr[(1 * TR + rr) * HID + tid]
                 + scr[(2 * TR + rr) * HID + tid] + scr[(3 * TR + rr) * HID + tid];
}

// ---------------------------------------------------------------------------
// SINGLE fused kernel, 256 blocks x 256 threads (1 block/CU, all co-resident).
// Phase 1: R11 streaming encoder -> score(f32), Ai/Aj(f16).
// Manual grid barrier: per-block flag +1 (lockstep across replays, poison-
// proof), each thread spins on one flag, 2 fences/block.
// Phase 2: 580 tasks (576 pair tiles + 4 softmax) strided over blocks.
// ---------------------------------------------------------------------------
__global__ __launch_bounds__(256) void fused_kernel(
    const float* __restrict__ cities,
    const float* __restrict__ We1, const float* __restrict__ be1,
    const float* __restrict__ We2, const float* __restrict__ be2,
    const float* __restrict__ Wa1, const float* __restrict__ ba1,
    const float* __restrict__ wa2, const float* __restrict__ ba2,
    const float* __restrict__ Wd1, const float* __restrict__ bd1,
    const float* __restrict__ wd2, const float* __restrict__ bd2,
    float* __restrict__ score, __half* __restrict__ Ai_h, __half* __restrict__ Aj_h,
    unsigned* __restrict__ flags,
    float* __restrict__ att, float* __restrict__ p)
{
    __shared__ float smem[8576];          // 33.5 KB, phase-overlaid
    __shared__ unsigned tgt_s;

    // phase-1 views
    float (*h1_s)[HID] = (float (*)[HID]) smem;            // 1536 f
    float (*emb_s)[DIM] = (float (*)[DIM])(smem + 1536);   // 768 f
    float* red2 = smem + 2304;                             // 24 f
    float* scr  = smem + 2432;                             // 6144 f

    const int tid = threadIdx.x;
    const int bid = blockIdx.x;
    const int r0  = bid * TR;

    // ==== PHASE 1: streaming encoder (R11 lineage, absmax-0.0) ==============
    {
        const float w0 = We1[tid], w1 = We1[HID + tid], b1v = be1[tid];
        #pragma unroll
        for (int rr = 0; rr < TR; ++rr) {
            const float cxx = cities[(r0 + rr) * 2];
            const float cyy = cities[(r0 + rr) * 2 + 1];
            h1_s[rr][tid] = fmaxf(fmaf(cxx, w0, fmaf(cyy, w1, b1v)), 0.f);
        }
    }
    __syncthreads();

    // emb = h1 @ We2 + be2 (k-split 8)
    {
        const int d4 = tid & 31;
        const int k0 = (tid >> 5) * 32;
        float4 acc[TR];
        #pragma unroll
        for (int rr = 0; rr < TR; ++rr) acc[rr] = make_float4(0.f, 0.f, 0.f, 0.f);

        #pragma unroll 2
        for (int kb = 0; kb < 32; kb += 4) {
            float4 hv[TR];
            #pragma unroll
            for (int rr = 0; rr < TR; ++rr)
                hv[rr] = *(const float4*)&h1_s[rr][k0 + kb];
            #pragma unroll
            for (int kk = 0; kk < 4; ++kk) {
                const float4 w4 = *(const float4*)&We2[(k0 + kb + kk) * DIM + d4 * 4];
                #pragma unroll
                for (int rr = 0; rr < TR; ++rr) {
                    const float h = ((const float*)&hv[rr])[kk];
                    acc[rr].x = fmaf(h, w4.x, acc[rr].x);
                    acc[rr].y = fmaf(h, w4.y, acc[rr].y);
                    acc[rr].z = fmaf(h, w4.z, acc[rr].z);
                    acc[rr].w = fmaf(h, w4.w, acc[rr].w);
                }
            }
        }
        #pragma unroll
        for (int rr = 0; rr < TR; ++rr) {
            acc[rr].x += __shfl_xor(acc[rr].x, 32);
            acc[rr].y += __shfl_xor(acc[rr].y, 32);
            acc[rr].z += __shfl_xor(acc[rr].z, 32);
            acc[rr].w += __shfl_xor(acc[rr].w, 32);
        }
        if ((tid & 63) < 32) {
            const int wv = tid >> 6;
            #pragma unroll
            for (int rr = 0; rr < TR; ++rr)
                *(float4*)&scr[(wv * TR + rr) * DIM + d4 * 4] = acc[rr];
        }
        __syncthreads();
        for (int o = tid; o < TR * DIM; o += 256) {
            const int rr = o >> 7, d = o & (DIM - 1);
            emb_s[rr][d] = scr[(0 * TR + rr) * DIM + d] + scr[(1 * TR + rr) * DIM + d]
                         + scr[(2 * TR + rr) * DIM + d] + scr[(3 * TR + rr) * DIM + d]
                         + be2[d];
        }
        __syncthreads();
    }

    float o6[TR];

    // Wa1 -> attention scores
    chunk_stream(Wa1, emb_s, scr, tid, o6);
    {
        const float ba1v = ba1[tid], wa2v = wa2[tid];
        const int wv = tid >> 6;
        #pragma unroll
        for (int rr = 0; rr < TR; ++rr) {
            float v = fmaxf(o6[rr] + ba1v, 0.f) * wa2v;
            #pragma unroll
            for (int off = 32; off > 0; off >>= 1)
                v += __shfl_down(v, off);
            if ((tid & 63) == 0) red2[wv * TR + rr] = v;
        }
        __syncthreads();
        if (tid < TR)
            score[r0 + tid] = red2[0 * TR + tid] + red2[1 * TR + tid]
                            + red2[2 * TR + tid] + red2[3 * TR + tid];
        // ba2 dropped: softmax is shift-invariant
    }

    // Wd1 rows 0..127 -> Ai (f16, RN — same rounding as old pair pack)
    chunk_stream(Wd1, emb_s, scr, tid, o6);
    {
        const float bd1v = bd1[tid];
        #pragma unroll
        for (int rr = 0; rr < TR; ++rr)
            Ai_h[(r0 + rr) * HID + tid] = __float2half(o6[rr] + bd1v);
    }

    // Wd1 rows 128..255 -> Aj (f16)
    chunk_stream(Wd1 + DIM * HID, emb_s, scr, tid, o6);
    #pragma unroll
    for (int rr = 0; rr < TR; ++rr)
        Aj_h[(r0 + rr) * HID + tid] = __float2half(o6[rr]);
    (void)ba2;

    // ==== GRID BARRIER (single, lockstep-flag, poison-proof) ================
    __threadfence();                       // release this thread's stores
    __syncthreads();
    if (tid == 0) {
        const unsigned oldv = __hip_atomic_load(&flags[bid], __ATOMIC_RELAXED,
                                                __HIP_MEMORY_SCOPE_AGENT);
        tgt_s = oldv + 1u;
        __hip_atomic_store(&flags[bid], oldv + 1u, __ATOMIC_RELEASE,
                           __HIP_MEMORY_SCOPE_AGENT);
    }
    __syncthreads();
    {
        const unsigned target = tgt_s;     // identical across all blocks
        while (__hip_atomic_load(&flags[tid], __ATOMIC_RELAXED,
                                 __HIP_MEMORY_SCOPE_AGENT) != target) {}
    }
    __threadfence();                       // acquire
    __syncthreads();

    // ==== PHASE 2: pair tiles + softmax =====================================
    const float bd = bd2[0];
    __half*   ai_s = (__half*)smem;            // 4096 f overlay
    __half*   aj_s = (__half*)smem + 32 * HID; // next 4096 f
    unsigned* wd2h = (unsigned*)(smem + 8192); // 128 u32
    float*    redm = smem + 8320;              // softmax scratch

    for (int t = bid; t < NTASK; t += NBLK) {
        __syncthreads();                       // LDS reuse guard
        if (t < 576) {
            const int b   = t / 144;
            const int rem = t % 144;
            const int i0  = (rem / 12) * 32;
            const int j0  = (rem % 12) * 32;

            if (tid < HID / 2) {
                const float2 w2 = *(const float2*)&wd2[tid * 2];
                wd2h[tid] = pack2(w2.x, w2.y);
            }
            for (int u = tid; u < 32 * 32; u += 256) {
                const int r = u >> 5, s = u & 31;
                const int su = (s ^ (r & 15)) * 8;
                *(float4*)&ai_s[r * HID + su] =
                    *(const float4*)&Ai_h[(b * NCITY + i0 + r) * HID + s * 8];
                *(float4*)&aj_s[r * HID + su] =
                    *(const float4*)&Aj_h[(b * NCITY + j0 + r) * HID + s * 8];
            }
            __syncthreads();

            const int tx = tid & 15;
            const int ty = tid >> 4;

            unsigned a00A = 0u, a00B = 0u, a01A = 0u, a01B = 0u;
            unsigned a10A = 0u, a10B = 0u, a11A = 0u, a11B = 0u;

            #pragma unroll 4
            for (int k8 = 0; k8 < 32; ++k8) {
                const int ci = (k8 ^ ty) * 8;
                const int cj = (k8 ^ tx) * 8;
                H8 x0, x1, y0, y1;
                x0.f4 = *(const float4*)&ai_s[ ty       * HID + ci];
                x1.f4 = *(const float4*)&ai_s[(ty + 16) * HID + ci];
                y0.f4 = *(const float4*)&aj_s[ tx       * HID + cj];
                y1.f4 = *(const float4*)&aj_s[(tx + 16) * HID + cj];

                #pragma unroll
                for (int q = 0; q < 4; ++q) {
                    const unsigned w = wd2h[k8 * 4 + q];
                    const unsigned t00 = pk_max0(pk_add(x0.u[q], y0.u[q]));
                    const unsigned t01 = pk_max0(pk_add(x0.u[q], y1.u[q]));
                    const unsigned t10 = pk_max0(pk_add(x1.u[q], y0.u[q]));
                    const unsigned t11 = pk_max0(pk_add(x1.u[q], y1.u[q]));
                    if (q < 2) {
                        a00A = pk_fma(t00, w, a00A);
                        a01A = pk_fma(t01, w, a01A);
                        a10A = pk_fma(t10, w, a10A);
                        a11A = pk_fma(t11, w, a11A);
                    } else {
                        a00B = pk_fma(t00, w, a00B);
                        a01B = pk_fma(t01, w, a01B);
                        a10B = pk_fma(t10, w, a10B);
                        a11B = pk_fma(t11, w, a11B);
                    }
                }
            }

            float accs[2][2];
            accs[0][0] = sum2(a00A) + sum2(a00B);
            accs[0][1] = sum2(a01A) + sum2(a01B);
            accs[1][0] = sum2(a10A) + sum2(a10B);
            accs[1][1] = sum2(a11A) + sum2(a11B);

            #pragma unroll
            for (int ii = 0; ii < 2; ++ii) {
                #pragma unroll
                for (int jj = 0; jj < 2; ++jj) {
                    const int gi = i0 + ty + ii * 16;
                    const int gj = j0 + tx + jj * 16;
                    const float v = 1.f / (1.f + __expf(-(accs[ii][jj] + bd)));
                    p[(b * NCITY + gi) * NCITY + gj] = (gi == gj) ? 0.f : v;
                }
            }
        } else {
            // softmax for batch bb
            const int bb = t - 576;
            const float v0 = score[bb * NCITY + tid];
            const bool  h2v = (tid < NCITY - 256);
            const float v1 = h2v ? score[bb * NCITY + 256 + tid] : -3.4e38f;
            float m = fmaxf(v0, v1);
            #pragma unroll
            for (int off = 32; off > 0; off >>= 1)
                m = fmaxf(m, __shfl_down(m, off));
            if ((tid & 63) == 0) redm[tid >> 6] = m;
            __syncthreads();
            m = fmaxf(fmaxf(redm[0], redm[1]), fmaxf(redm[2], redm[3]));
            const float e0 = __expf(v0 - m);
            const float e1 = h2v ? __expf(v1 - m) : 0.f;
            float s = e0 + e1;
            #pragma unroll
            for (int off = 32; off > 0; off >>= 1)
                s += __shfl_down(s, off);
            if ((tid & 63) == 0) redm[4 + (tid >> 6)] = s;
            __syncthreads();
            s = redm[4] + redm[5] + redm[6] + redm[7];
            att[bb * NCITY + tid] = e0 / s;
            if (h2v) att[bb * NCITY + 256 + tid] = e1 / s;
        }
    }
}

// ---------------------------------------------------------------------------
extern "C" void kernel_launch(void* const* d_in, const int* in_sizes, int n_in,
                              void* d_out, int out_size, void* d_ws, size_t ws_size,
                              hipStream_t stream)
{
    const float* cities = (const float*)d_in[0];
    const float* We1    = (const float*)d_in[1];
    const float* be1    = (const float*)d_in[2];
    const float* We2    = (const float*)d_in[3];
    const float* be2    = (const float*)d_in[4];
    const float* Wa1    = (const float*)d_in[5];
    const float* ba1    = (const float*)d_in[6];
    const float* wa2    = (const float*)d_in[7];
    const float* ba2    = (const float*)d_in[8];
    const float* Wd1    = (const float*)d_in[9];
    const float* bd1    = (const float*)d_in[10];
    const float* wd2    = (const float*)d_in[11];
    const float* bd2    = (const float*)d_in[12];

    float* out_att = (float*)d_out;                 // [4,384]
    float* out_p   = out_att + M_TOT;               // [4,384,384]

    float*    score = (float*)d_ws;                           // 1536 f32
    __half*   Ai_h  = (__half*)(score + M_TOT);               // 1536*256 f16
    __half*   Aj_h  = Ai_h + M_TOT * HID;                     // 1536*256 f16
    unsigned* flags = (unsigned*)(Aj_h + M_TOT * HID);        // 256 u32

    fused_kernel<<<NBLK, 256, 0, stream>>>(
        cities, We1, be1, We2, be2, Wa1, ba1, wa2, ba2, Wd1, bd1, wd2, bd2,
        score, Ai_h, Aj_h, flags, out_att, out_p);
}

// Round 14
// 41.705 us; speedup vs baseline: 1.9104x; 1.9104x over previous
//
#include <hip/hip_runtime.h>
#include <hip/hip_fp16.h>

#define NCITY 384
#define BATCH 4
#define DIM   128
#define HID   256
#define M_TOT (BATCH * NCITY)   // 1536
#define TR    6                 // rows per block -> 256 blocks == 256 CUs
#define NBLK  (M_TOT / TR)      // 256
#define NTASK (576 + BATCH)     // 576 pair tiles + 4 softmax

// ---------------------------------------------------------------------------
// packed f16 helpers (raw VOP3P; ROCm header __hmax2 broken on gfx950)
// ---------------------------------------------------------------------------
__device__ __forceinline__ unsigned pk_add(unsigned a, unsigned b) {
    unsigned r; asm("v_pk_add_f16 %0, %1, %2" : "=v"(r) : "v"(a), "v"(b)); return r;
}
__device__ __forceinline__ unsigned pk_max0(unsigned a) {
    unsigned r; asm("v_pk_max_f16 %0, %1, %2" : "=v"(r) : "v"(a), "v"(0u)); return r;
}
__device__ __forceinline__ unsigned pk_fma(unsigned a, unsigned b, unsigned c) {
    unsigned r; asm("v_pk_fma_f16 %0, %1, %2, %3" : "=v"(r) : "v"(a), "v"(b), "v"(c)); return r;
}
__device__ __forceinline__ unsigned pack2(float a, float b) {
    union { __half2 h2; unsigned u; } c;
    c.h2 = __float22half2_rn(make_float2(a, b));
    return c.u;
}
__device__ __forceinline__ float sum2(unsigned u) {
    union { unsigned u; __half2 h2; } c; c.u = u;
    return __low2float(c.h2) + __high2float(c.h2);
}
__device__ __forceinline__ unsigned short h_bits(float x) {
    union { __half h; unsigned short s; } c;
    c.h = __float2half(x);
    return c.s;
}
union H8 { float4 f4; unsigned u[4]; };

// ---------------------------------------------------------------------------
// streaming head-chunk GEMM (R11-proven): W[128][256] from global, k-split 4,
// cross-wave reduce through LDS scratch.
// ---------------------------------------------------------------------------
__device__ __forceinline__ void chunk_stream(
    const float* __restrict__ W,
    const float (*emb_s)[DIM], float* scr, int tid, float out6[TR])
{
    const int c4 = tid & 63;
    const int wv = tid >> 6;
    const int k0 = wv * 32;

    float4 acc[TR];
    #pragma unroll
    for (int rr = 0; rr < TR; ++rr) acc[rr] = make_float4(0.f, 0.f, 0.f, 0.f);

    #pragma unroll 2
    for (int kb = 0; kb < 32; kb += 4) {
        float4 ev[TR];
        #pragma unroll
        for (int rr = 0; rr < TR; ++rr)
            ev[rr] = *(const float4*)&emb_s[rr][k0 + kb];
        #pragma unroll
        for (int kk = 0; kk < 4; ++kk) {
            const float4 w4 = *(const float4*)&W[(k0 + kb + kk) * HID + c4 * 4];
            #pragma unroll
            for (int rr = 0; rr < TR; ++rr) {
                const float e = ((const float*)&ev[rr])[kk];
                acc[rr].x = fmaf(e, w4.x, acc[rr].x);
                acc[rr].y = fmaf(e, w4.y, acc[rr].y);
                acc[rr].z = fmaf(e, w4.z, acc[rr].z);
                acc[rr].w = fmaf(e, w4.w, acc[rr].w);
            }
        }
    }
    __syncthreads();
    #pragma unroll
    for (int rr = 0; rr < TR; ++rr)
        *(float4*)&scr[(wv * TR + rr) * HID + c4 * 4] = acc[rr];
    __syncthreads();
    #pragma unroll
    for (int rr = 0; rr < TR; ++rr)
        out6[rr] = scr[(0 * TR + rr) * HID + tid] + scr[(1 * TR + rr) * HID + tid]
                 + scr[(2 * TR + rr) * HID + tid] + scr[(3 * TR + rr) * HID + tid];
}

// ---------------------------------------------------------------------------
// SINGLE fused kernel, 256 blocks x 256 threads (1 block/CU, all co-resident).
// Phase 1: R11 streaming encoder -> score/Ai/Aj via NON-TEMPORAL stores
//   (no-allocate -> lines bypass the non-coherent L2 to memory-side LLC).
// Barrier: vmcnt-drained relaxed flag store (+1 lockstep, poison-proof) +
//   per-thread poll with s_sleep. NO __threadfence / release atomics — those
//   compile to buffer_wbl2/inv and cost ~60-100 us (R10/R12 post-mortems).
// Phase 2: 580 tasks; consumer loads are normal.
// ---------------------------------------------------------------------------
__global__ __launch_bounds__(256) void fused_kernel(
    const float* __restrict__ cities,
    const float* __restrict__ We1, const float* __restrict__ be1,
    const float* __restrict__ We2, const float* __restrict__ be2,
    const float* __restrict__ Wa1, const float* __restrict__ ba1,
    const float* __restrict__ wa2, const float* __restrict__ ba2,
    const float* __restrict__ Wd1, const float* __restrict__ bd1,
    const float* __restrict__ wd2, const float* __restrict__ bd2,
    float* __restrict__ score, __half* __restrict__ Ai_h, __half* __restrict__ Aj_h,
    unsigned* __restrict__ flags,
    float* __restrict__ att, float* __restrict__ p)
{
    __shared__ float smem[8576];          // 33.5 KB, phase-overlaid
    __shared__ unsigned tgt_s;

    float (*h1_s)[HID] = (float (*)[HID]) smem;            // 1536 f
    float (*emb_s)[DIM] = (float (*)[DIM])(smem + 1536);   // 768 f
    float* red2 = smem + 2304;                             // 24 f
    float* scr  = smem + 2432;                             // 6144 f

    const int tid = threadIdx.x;
    const int bid = blockIdx.x;
    const int r0  = bid * TR;

    // ==== PHASE 1: streaming encoder (R11 lineage, absmax-0.0) ==============
    {
        const float w0 = We1[tid], w1 = We1[HID + tid], b1v = be1[tid];
        #pragma unroll
        for (int rr = 0; rr < TR; ++rr) {
            const float cxx = cities[(r0 + rr) * 2];
            const float cyy = cities[(r0 + rr) * 2 + 1];
            h1_s[rr][tid] = fmaxf(fmaf(cxx, w0, fmaf(cyy, w1, b1v)), 0.f);
        }
    }
    __syncthreads();

    // emb = h1 @ We2 + be2 (k-split 8)
    {
        const int d4 = tid & 31;
        const int k0 = (tid >> 5) * 32;
        float4 acc[TR];
        #pragma unroll
        for (int rr = 0; rr < TR; ++rr) acc[rr] = make_float4(0.f, 0.f, 0.f, 0.f);

        #pragma unroll 2
        for (int kb = 0; kb < 32; kb += 4) {
            float4 hv[TR];
            #pragma unroll
            for (int rr = 0; rr < TR; ++rr)
                hv[rr] = *(const float4*)&h1_s[rr][k0 + kb];
            #pragma unroll
            for (int kk = 0; kk < 4; ++kk) {
                const float4 w4 = *(const float4*)&We2[(k0 + kb + kk) * DIM + d4 * 4];
                #pragma unroll
                for (int rr = 0; rr < TR; ++rr) {
                    const float h = ((const float*)&hv[rr])[kk];
                    acc[rr].x = fmaf(h, w4.x, acc[rr].x);
                    acc[rr].y = fmaf(h, w4.y, acc[rr].y);
                    acc[rr].z = fmaf(h, w4.z, acc[rr].z);
                    acc[rr].w = fmaf(h, w4.w, acc[rr].w);
                }
            }
        }
        #pragma unroll
        for (int rr = 0; rr < TR; ++rr) {
            acc[rr].x += __shfl_xor(acc[rr].x, 32);
            acc[rr].y += __shfl_xor(acc[rr].y, 32);
            acc[rr].z += __shfl_xor(acc[rr].z, 32);
            acc[rr].w += __shfl_xor(acc[rr].w, 32);
        }
        if ((tid & 63) < 32) {
            const int wv = tid >> 6;
            #pragma unroll
            for (int rr = 0; rr < TR; ++rr)
                *(float4*)&scr[(wv * TR + rr) * DIM + d4 * 4] = acc[rr];
        }
        __syncthreads();
        for (int o = tid; o < TR * DIM; o += 256) {
            const int rr = o >> 7, d = o & (DIM - 1);
            emb_s[rr][d] = scr[(0 * TR + rr) * DIM + d] + scr[(1 * TR + rr) * DIM + d]
                         + scr[(2 * TR + rr) * DIM + d] + scr[(3 * TR + rr) * DIM + d]
                         + be2[d];
        }
        __syncthreads();
    }

    float o6[TR];

    // Wa1 -> attention scores (nt store)
    chunk_stream(Wa1, emb_s, scr, tid, o6);
    {
        const float ba1v = ba1[tid], wa2v = wa2[tid];
        const int wv = tid >> 6;
        #pragma unroll
        for (int rr = 0; rr < TR; ++rr) {
            float v = fmaxf(o6[rr] + ba1v, 0.f) * wa2v;
            #pragma unroll
            for (int off = 32; off > 0; off >>= 1)
                v += __shfl_down(v, off);
            if ((tid & 63) == 0) red2[wv * TR + rr] = v;
        }
        __syncthreads();
        if (tid < TR)
            __builtin_nontemporal_store(
                red2[0 * TR + tid] + red2[1 * TR + tid]
              + red2[2 * TR + tid] + red2[3 * TR + tid], &score[r0 + tid]);
        // ba2 dropped: softmax is shift-invariant
    }

    // Wd1 rows 0..127 -> Ai (f16 RN bits, nt store via u16)
    chunk_stream(Wd1, emb_s, scr, tid, o6);
    {
        const float bd1v = bd1[tid];
        unsigned short* Ai_u = (unsigned short*)Ai_h;
        #pragma unroll
        for (int rr = 0; rr < TR; ++rr)
            __builtin_nontemporal_store(h_bits(o6[rr] + bd1v),
                                        &Ai_u[(r0 + rr) * HID + tid]);
    }

    // Wd1 rows 128..255 -> Aj (f16 RN bits, nt store via u16)
    chunk_stream(Wd1 + DIM * HID, emb_s, scr, tid, o6);
    {
        unsigned short* Aj_u = (unsigned short*)Aj_h;
        #pragma unroll
        for (int rr = 0; rr < TR; ++rr)
            __builtin_nontemporal_store(h_bits(o6[rr]),
                                        &Aj_u[(r0 + rr) * HID + tid]);
    }
    (void)ba2;

    // ==== GRID BARRIER: no cache fences, nt data already at LLC =============
    asm volatile("s_waitcnt vmcnt(0)" ::: "memory");   // all nt stores acked
    __syncthreads();                                   // every wave drained
    if (tid == 0) {
        const unsigned oldv = __hip_atomic_load(&flags[bid], __ATOMIC_RELAXED,
                                                __HIP_MEMORY_SCOPE_AGENT);
        tgt_s = oldv + 1u;
        __hip_atomic_store(&flags[bid], oldv + 1u, __ATOMIC_RELAXED,
                           __HIP_MEMORY_SCOPE_AGENT);
    }
    __syncthreads();
    {
        const unsigned target = tgt_s;     // identical across all blocks
        while (__hip_atomic_load(&flags[tid], __ATOMIC_RELAXED,
                                 __HIP_MEMORY_SCOPE_AGENT) != target)
            __builtin_amdgcn_s_sleep(2);
    }
    __builtin_amdgcn_sched_barrier(0);
    __syncthreads();

    // ==== PHASE 2: pair tiles + softmax =====================================
    const float bd = bd2[0];
    __half*   ai_s = (__half*)smem;            // 4096 f overlay
    __half*   aj_s = (__half*)smem + 32 * HID;
    unsigned* wd2h = (unsigned*)(smem + 8192); // 128 u32
    float*    redm = smem + 8320;

    if (tid < HID / 2) {                       // pack wd2 once
        const float2 w2 = *(const float2*)&wd2[tid * 2];
        wd2h[tid] = pack2(w2.x, w2.y);
    }

    for (int t = bid; t < NTASK; t += NBLK) {
        __syncthreads();                       // LDS reuse guard
        if (t < 576) {
            const int b   = t / 144;
            const int rem = t % 144;
            const int i0  = (rem / 12) * 32;
            const int j0  = (rem % 12) * 32;

            for (int u = tid; u < 32 * 32; u += 256) {
                const int r = u >> 5, s = u & 31;
                const int su = (s ^ (r & 15)) * 8;
                *(float4*)&ai_s[r * HID + su] =
                    *(const float4*)&Ai_h[(b * NCITY + i0 + r) * HID + s * 8];
                *(float4*)&aj_s[r * HID + su] =
                    *(const float4*)&Aj_h[(b * NCITY + j0 + r) * HID + s * 8];
            }
            __syncthreads();

            const int tx = tid & 15;
            const int ty = tid >> 4;

            unsigned a00A = 0u, a00B = 0u, a01A = 0u, a01B = 0u;
            unsigned a10A = 0u, a10B = 0u, a11A = 0u, a11B = 0u;

            #pragma unroll 4
            for (int k8 = 0; k8 < 32; ++k8) {
                const int ci = (k8 ^ ty) * 8;
                const int cj = (k8 ^ tx) * 8;
                H8 x0, x1, y0, y1;
                x0.f4 = *(const float4*)&ai_s[ ty       * HID + ci];
                x1.f4 = *(const float4*)&ai_s[(ty + 16) * HID + ci];
                y0.f4 = *(const float4*)&aj_s[ tx       * HID + cj];
                y1.f4 = *(const float4*)&aj_s[(tx + 16) * HID + cj];

                #pragma unroll
                for (int q = 0; q < 4; ++q) {
                    const unsigned w = wd2h[k8 * 4 + q];
                    const unsigned t00 = pk_max0(pk_add(x0.u[q], y0.u[q]));
                    const unsigned t01 = pk_max0(pk_add(x0.u[q], y1.u[q]));
                    const unsigned t10 = pk_max0(pk_add(x1.u[q], y0.u[q]));
                    const unsigned t11 = pk_max0(pk_add(x1.u[q], y1.u[q]));
                    if (q < 2) {
                        a00A = pk_fma(t00, w, a00A);
                        a01A = pk_fma(t01, w, a01A);
                        a10A = pk_fma(t10, w, a10A);
                        a11A = pk_fma(t11, w, a11A);
                    } else {
                        a00B = pk_fma(t00, w, a00B);
                        a01B = pk_fma(t01, w, a01B);
                        a10B = pk_fma(t10, w, a10B);
                        a11B = pk_fma(t11, w, a11B);
                    }
                }
            }

            float accs[2][2];
            accs[0][0] = sum2(a00A) + sum2(a00B);
            accs[0][1] = sum2(a01A) + sum2(a01B);
            accs[1][0] = sum2(a10A) + sum2(a10B);
            accs[1][1] = sum2(a11A) + sum2(a11B);

            #pragma unroll
            for (int ii = 0; ii < 2; ++ii) {
                #pragma unroll
                for (int jj = 0; jj < 2; ++jj) {
                    const int gi = i0 + ty + ii * 16;
                    const int gj = j0 + tx + jj * 16;
                    const float v = 1.f / (1.f + __expf(-(accs[ii][jj] + bd)));
                    p[(b * NCITY + gi) * NCITY + gj] = (gi == gj) ? 0.f : v;
                }
            }
        } else {
            const int bb = t - 576;
            const float v0 = score[bb * NCITY + tid];
            const bool  h2v = (tid < NCITY - 256);
            const float v1 = h2v ? score[bb * NCITY + 256 + tid] : -3.4e38f;
            float m = fmaxf(v0, v1);
            #pragma unroll
            for (int off = 32; off > 0; off >>= 1)
                m = fmaxf(m, __shfl_down(m, off));
            if ((tid & 63) == 0) redm[tid >> 6] = m;
            __syncthreads();
            m = fmaxf(fmaxf(redm[0], redm[1]), fmaxf(redm[2], redm[3]));
            const float e0 = __expf(v0 - m);
            const float e1 = h2v ? __expf(v1 - m) : 0.f;
            float s = e0 + e1;
            #pragma unroll
            for (int off = 32; off > 0; off >>= 1)
                s += __shfl_down(s, off);
            if ((tid & 63) == 0) redm[4 + (tid >> 6)] = s;
            __syncthreads();
            s = redm[4] + redm[5] + redm[6] + redm[7];
            att[bb * NCITY + tid] = e0 / s;
            if (h2v) att[bb * NCITY + 256 + tid] = e1 / s;
        }
    }
}

// ---------------------------------------------------------------------------
extern "C" void kernel_launch(void* const* d_in, const int* in_sizes, int n_in,
                              void* d_out, int out_size, void* d_ws, size_t ws_size,
                              hipStream_t stream)
{
    const float* cities = (const float*)d_in[0];
    const float* We1    = (const float*)d_in[1];
    const float* be1    = (const float*)d_in[2];
    const float* We2    = (const float*)d_in[3];
    const float* be2    = (const float*)d_in[4];
    const float* Wa1    = (const float*)d_in[5];
    const float* ba1    = (const float*)d_in[6];
    const float* wa2    = (const float*)d_in[7];
    const float* ba2    = (const float*)d_in[8];
    const float* Wd1    = (const float*)d_in[9];
    const float* bd1    = (const float*)d_in[10];
    const float* wd2    = (const float*)d_in[11];
    const float* bd2    = (const float*)d_in[12];

    float* out_att = (float*)d_out;                 // [4,384]
    float* out_p   = out_att + M_TOT;               // [4,384,384]

    float*    score = (float*)d_ws;                           // 1536 f32
    __half*   Ai_h  = (__half*)(score + M_TOT);               // 1536*256 f16
    __half*   Aj_h  = Ai_h + M_TOT * HID;                     // 1536*256 f16
    unsigned* flags = (unsigned*)(Aj_h + M_TOT * HID);        // 256 u32

    fused_kernel<<<NBLK, 256, 0, stream>>>(
        cities, We1, be1, We2, be2, Wa1, ba1, wa2, ba2, Wd1, bd1, wd2, bd2,
        score, Ai_h, Aj_h, flags, out_att, out_p);
}

// Round 15
// 39.646 us; speedup vs baseline: 2.0096x; 1.0519x over previous
//
#include <hip/hip_runtime.h>
#include <hip/hip_fp16.h>

#define NCITY 384
#define BATCH 4
#define DIM   128
#define HID   256
#define M_TOT 1536
#define TR    6

typedef unsigned short u16;

// ---------------------------------------------------------------------------
// packed f16 helpers (raw VOP3P; ROCm header __hmax2 broken on gfx950)
// ---------------------------------------------------------------------------
__device__ __forceinline__ unsigned pk_add(unsigned a, unsigned b) {
    unsigned r; asm("v_pk_add_f16 %0, %1, %2" : "=v"(r) : "v"(a), "v"(b)); return r;
}
__device__ __forceinline__ unsigned pk_max0(unsigned a) {
    unsigned r; asm("v_pk_max_f16 %0, %1, %2" : "=v"(r) : "v"(a), "v"(0u)); return r;
}
__device__ __forceinline__ unsigned pk_fma(unsigned a, unsigned b, unsigned c) {
    unsigned r; asm("v_pk_fma_f16 %0, %1, %2, %3" : "=v"(r) : "v"(a), "v"(b), "v"(c)); return r;
}
__device__ __forceinline__ unsigned pack2(float a, float b) {
    union { __half2 h2; unsigned u; } c;
    c.h2 = __float22half2_rn(make_float2(a, b));
    return c.u;
}
__device__ __forceinline__ float sum2(unsigned u) {
    union { unsigned u; __half2 h2; } c; c.u = u;
    return __low2float(c.h2) + __high2float(c.h2);
}
__device__ __forceinline__ u16 h_bits(float x) {
    union { __half h; u16 s; } c;
    c.h = __float2half(x);
    return c.s;
}
union H8 { float4 f4; unsigned u[4]; };

// ---------------------------------------------------------------------------
// K0: convert weights f32 -> f16 into ws.
//   We2h [256][128]; Wh [128][768] = [Wa1 | Wd1[:128] | Wd1[128:]] col-concat.
// 65536 u32 outputs, one per thread (grid 256 x 256).
// ---------------------------------------------------------------------------
__global__ __launch_bounds__(256) void convert_kernel(
    const float* __restrict__ We2, const float* __restrict__ Wa1,
    const float* __restrict__ Wd1,
    unsigned* __restrict__ We2h_u, unsigned* __restrict__ Wh_u)
{
    const int i = blockIdx.x * 256 + threadIdx.x;   // 0..65535
    if (i < 16384) {
        const float2 f = *(const float2*)&We2[2 * i];
        We2h_u[i] = pack2(f.x, f.y);
    } else {
        const int j = i - 16384;                    // 0..49151
        const int k = j / 384;
        const int t = j - k * 384;
        const int n = 2 * t;
        const float* src;
        if (n < 256)      src = &Wa1[k * 256 + n];
        else if (n < 512) src = &Wd1[k * 256 + (n - 256)];
        else              src = &Wd1[(128 + k) * 256 + (n - 512)];
        const float2 f = *(const float2*)src;
        Wh_u[j] = pack2(f.x, f.y);
    }
}

// ---------------------------------------------------------------------------
// K1: emb = relu(cities@We1+be1) @ We2h + be2 -> emb_h (f16).
// R11-proven structure; We2 now f16 (halves the per-CU byte stream).
// grid 256, TR=6 rows/block.
// ---------------------------------------------------------------------------
__global__ __launch_bounds__(256) void emb_kernel(
    const float* __restrict__ cities,
    const float* __restrict__ We1, const float* __restrict__ be1,
    const u16* __restrict__ We2h, const float* __restrict__ be2,
    u16* __restrict__ emb_h)
{
    __shared__ float h1_s[TR][HID];       // 6 KB
    __shared__ float scr[4 * TR * DIM];   // 12 KB

    const int tid = threadIdx.x;
    const int r0  = blockIdx.x * TR;

    {
        const float w0 = We1[tid], w1 = We1[HID + tid], b1v = be1[tid];
        #pragma unroll
        for (int rr = 0; rr < TR; ++rr) {
            const float cxx = cities[(r0 + rr) * 2];
            const float cyy = cities[(r0 + rr) * 2 + 1];
            h1_s[rr][tid] = fmaxf(fmaf(cxx, w0, fmaf(cyy, w1, b1v)), 0.f);
        }
    }
    __syncthreads();

    const int d4 = tid & 31;              // 4 cols: 4*d4
    const int k0 = (tid >> 5) * 32;       // 8 k-groups
    float4 acc[TR];
    #pragma unroll
    for (int rr = 0; rr < TR; ++rr) acc[rr] = make_float4(0.f, 0.f, 0.f, 0.f);

    #pragma unroll 2
    for (int kb = 0; kb < 32; kb += 4) {
        float4 hv[TR];
        #pragma unroll
        for (int rr = 0; rr < TR; ++rr)
            hv[rr] = *(const float4*)&h1_s[rr][k0 + kb];
        #pragma unroll
        for (int kk = 0; kk < 4; ++kk) {
            const u16* wp = &We2h[(k0 + kb + kk) * DIM + d4 * 4];
            const float2 w01 = __half22float2(*(const __half2*)wp);
            const float2 w23 = __half22float2(*(const __half2*)(wp + 2));
            #pragma unroll
            for (int rr = 0; rr < TR; ++rr) {
                const float h = ((const float*)&hv[rr])[kk];
                acc[rr].x = fmaf(h, w01.x, acc[rr].x);
                acc[rr].y = fmaf(h, w01.y, acc[rr].y);
                acc[rr].z = fmaf(h, w23.x, acc[rr].z);
                acc[rr].w = fmaf(h, w23.y, acc[rr].w);
            }
        }
    }
    #pragma unroll
    for (int rr = 0; rr < TR; ++rr) {
        acc[rr].x += __shfl_xor(acc[rr].x, 32);
        acc[rr].y += __shfl_xor(acc[rr].y, 32);
        acc[rr].z += __shfl_xor(acc[rr].z, 32);
        acc[rr].w += __shfl_xor(acc[rr].w, 32);
    }
    if ((tid & 63) < 32) {
        const int wv = tid >> 6;
        #pragma unroll
        for (int rr = 0; rr < TR; ++rr)
            *(float4*)&scr[(wv * TR + rr) * DIM + d4 * 4] = acc[rr];
    }
    __syncthreads();
    #pragma unroll
    for (int j = 0; j < 3; ++j) {
        const int o = tid + j * 256;
        const int rr = o >> 7, d = o & (DIM - 1);
        const float v = scr[(0 * TR + rr) * DIM + d] + scr[(1 * TR + rr) * DIM + d]
                      + scr[(2 * TR + rr) * DIM + d] + scr[(3 * TR + rr) * DIM + d]
                      + be2[d];
        emb_h[(r0 + rr) * DIM + d] = h_bits(v);
    }
}

// ---------------------------------------------------------------------------
// K2: heads GEMM, all-f16 pk_fma: C[1536 x 768] = emb_h @ Wh, tiled 64 x 128.
// grid (6 n-groups, 24 m-tiles), 256 thr, 32 out/thread (4 rows x 8 cols).
// LDS: A as [d2][64 r] u32 (k-pair interleave), B as [k2][128 c] u32.
// Segments: g 0-1 att (relu*wa2 row-reduce -> score_part), 2-3 Ai(+bd1), 4-5 Aj.
// ---------------------------------------------------------------------------
__global__ __launch_bounds__(256) void heads_kernel(
    const u16* __restrict__ emb_h, const u16* __restrict__ Wh,
    const float* __restrict__ ba1, const float* __restrict__ wa2,
    const float* __restrict__ bd1,
    float* __restrict__ score_part,
    u16* __restrict__ Ai_u, u16* __restrict__ Aj_u)
{
    __shared__ unsigned lds_a[64 * 64];    // 16 KB
    __shared__ unsigned lds_b[64 * 128];   // 32 KB

    const int tid = threadIdx.x;
    const int g   = blockIdx.x;            // 0..5
    const int r0  = blockIdx.y * 64;
    const int n0  = g * 128;

    {   // stage A: emb rows r0..r0+63, u32 = (d even, d odd) pair
        const int r = tid & 63, dg = tid >> 6;
        #pragma unroll
        for (int v = 0; v < 4; ++v) {
            const uint4 q = *(const uint4*)&emb_h[(r0 + r) * DIM + dg * 32 + v * 8];
            const int d2 = dg * 16 + v * 4;
            lds_a[(d2 + 0) * 64 + r] = q.x;
            lds_a[(d2 + 1) * 64 + r] = q.y;
            lds_a[(d2 + 2) * 64 + r] = q.z;
            lds_a[(d2 + 3) * 64 + r] = q.w;
        }
    }
    {   // stage B: interleave rows 2k2,2k2+1 of Wh into (k even, k odd) u32
        const int c8 = tid & 15, k2g = tid >> 4;
        #pragma unroll
        for (int v = 0; v < 4; ++v) {
            const int k2 = k2g * 4 + v;
            const uint4 q0 = *(const uint4*)&Wh[(2 * k2)     * 768 + n0 + c8 * 8];
            const uint4 q1 = *(const uint4*)&Wh[(2 * k2 + 1) * 768 + n0 + c8 * 8];
            uint4 lo, hi;
            lo.x = (q0.x & 0xffffu) | (q1.x << 16);
            lo.y = (q0.x >> 16)     | (q1.x & 0xffff0000u);
            lo.z = (q0.y & 0xffffu) | (q1.y << 16);
            lo.w = (q0.y >> 16)     | (q1.y & 0xffff0000u);
            hi.x = (q0.z & 0xffffu) | (q1.z << 16);
            hi.y = (q0.z >> 16)     | (q1.z & 0xffff0000u);
            hi.z = (q0.w & 0xffffu) | (q1.w << 16);
            hi.w = (q0.w >> 16)     | (q1.w & 0xffff0000u);
            *(uint4*)&lds_b[k2 * 128 + c8 * 8]     = lo;
            *(uint4*)&lds_b[k2 * 128 + c8 * 8 + 4] = hi;
        }
    }
    __syncthreads();

    const int tx = tid & 15;               // col octet
    const int ty = tid >> 4;               // row quad
    unsigned acc[4][8] = {};

    #pragma unroll 4
    for (int k2 = 0; k2 < 64; ++k2) {
        const uint4 a  = *(const uint4*)&lds_a[k2 * 64 + ty * 4];
        const uint4 b0 = *(const uint4*)&lds_b[k2 * 128 + tx * 8];
        const uint4 b1 = *(const uint4*)&lds_b[k2 * 128 + tx * 8 + 4];
        const unsigned aa[4] = {a.x, a.y, a.z, a.w};
        const unsigned bb[8] = {b0.x, b0.y, b0.z, b0.w, b1.x, b1.y, b1.z, b1.w};
        #pragma unroll
        for (int i = 0; i < 4; ++i)
            #pragma unroll
            for (int j = 0; j < 8; ++j)
                acc[i][j] = pk_fma(aa[i], bb[j], acc[i][j]);
    }

    float out[4][8];
    #pragma unroll
    for (int i = 0; i < 4; ++i)
        #pragma unroll
        for (int j = 0; j < 8; ++j)
            out[i][j] = sum2(acc[i][j]);

    if (g < 2) {
        float ba[8], wa[8];
        *(float4*)&ba[0] = *(const float4*)&ba1[n0 + tx * 8];
        *(float4*)&ba[4] = *(const float4*)&ba1[n0 + tx * 8 + 4];
        *(float4*)&wa[0] = *(const float4*)&wa2[n0 + tx * 8];
        *(float4*)&wa[4] = *(const float4*)&wa2[n0 + tx * 8 + 4];
        #pragma unroll
        for (int i = 0; i < 4; ++i) {
            float s = 0.f;
            #pragma unroll
            for (int j = 0; j < 8; ++j)
                s += fmaxf(out[i][j] + ba[j], 0.f) * wa[j];
            s += __shfl_xor(s, 1);
            s += __shfl_xor(s, 2);
            s += __shfl_xor(s, 4);
            s += __shfl_xor(s, 8);
            if (tx == 0)
                score_part[g * M_TOT + r0 + ty * 4 + i] = s;
        }
    } else if (g < 4) {
        const int c0 = (g - 2) * 128 + tx * 8;
        float bd[8];
        *(float4*)&bd[0] = *(const float4*)&bd1[c0];
        *(float4*)&bd[4] = *(const float4*)&bd1[c0 + 4];
        #pragma unroll
        for (int i = 0; i < 4; ++i) {
            uint4 o;
            o.x = (unsigned)h_bits(out[i][0] + bd[0]) | ((unsigned)h_bits(out[i][1] + bd[1]) << 16);
            o.y = (unsigned)h_bits(out[i][2] + bd[2]) | ((unsigned)h_bits(out[i][3] + bd[3]) << 16);
            o.z = (unsigned)h_bits(out[i][4] + bd[4]) | ((unsigned)h_bits(out[i][5] + bd[5]) << 16);
            o.w = (unsigned)h_bits(out[i][6] + bd[6]) | ((unsigned)h_bits(out[i][7] + bd[7]) << 16);
            *(uint4*)&Ai_u[(r0 + ty * 4 + i) * HID + c0] = o;
        }
    } else {
        const int c0 = (g - 4) * 128 + tx * 8;
        #pragma unroll
        for (int i = 0; i < 4; ++i) {
            uint4 o;
            o.x = (unsigned)h_bits(out[i][0]) | ((unsigned)h_bits(out[i][1]) << 16);
            o.y = (unsigned)h_bits(out[i][2]) | ((unsigned)h_bits(out[i][3]) << 16);
            o.z = (unsigned)h_bits(out[i][4]) | ((unsigned)h_bits(out[i][5]) << 16);
            o.w = (unsigned)h_bits(out[i][6]) | ((unsigned)h_bits(out[i][7]) << 16);
            *(uint4*)&Aj_u[(r0 + ty * 4 + i) * HID + c0] = o;
        }
    }
}

// ---------------------------------------------------------------------------
// K3: pairwise decoder (f16, proven) + fused softmax (sums 2 score partials).
// grid (145, 4).
// ---------------------------------------------------------------------------
__global__ __launch_bounds__(256) void pair_sm_kernel(
    const __half* __restrict__ Ai, const __half* __restrict__ Aj,
    const float* __restrict__ wd2, const float* __restrict__ bd2,
    const float* __restrict__ sp, float* __restrict__ att,
    float* __restrict__ p)
{
    const int tid = threadIdx.x;
    const int b   = blockIdx.y;

    if (blockIdx.x == 144) {     // ---- softmax block for batch b ------------
        __shared__ float red[8];
        const int t = tid;
        const float v0 = sp[b * NCITY + t] + sp[M_TOT + b * NCITY + t];
        const bool  h2v = (t < NCITY - 256);
        const float v1 = h2v ? (sp[b * NCITY + 256 + t] + sp[M_TOT + b * NCITY + 256 + t])
                             : -3.4e38f;
        float m = fmaxf(v0, v1);
        #pragma unroll
        for (int off = 32; off > 0; off >>= 1)
            m = fmaxf(m, __shfl_down(m, off));
        if ((t & 63) == 0) red[t >> 6] = m;
        __syncthreads();
        m = fmaxf(fmaxf(red[0], red[1]), fmaxf(red[2], red[3]));
        const float e0 = __expf(v0 - m);
        const float e1 = h2v ? __expf(v1 - m) : 0.f;
        float s = e0 + e1;
        #pragma unroll
        for (int off = 32; off > 0; off >>= 1)
            s += __shfl_down(s, off);
        if ((t & 63) == 0) red[4 + (t >> 6)] = s;
        __syncthreads();
        s = red[4] + red[5] + red[6] + red[7];
        att[b * NCITY + t] = e0 / s;
        if (h2v) att[b * NCITY + 256 + t] = e1 / s;
        return;
    }

    __shared__ __half ai_s[32 * HID];    // 16 KB
    __shared__ __half aj_s[32 * HID];    // 16 KB
    __shared__ unsigned wd2h[HID / 2];   // 512 B

    const int i0 = (blockIdx.x / 12) * 32;
    const int j0 = (blockIdx.x % 12) * 32;

    if (tid < HID / 2) {
        const float2 w2 = *(const float2*)&wd2[tid * 2];
        wd2h[tid] = pack2(w2.x, w2.y);
    }

    for (int u = tid; u < 32 * 32; u += 256) {
        const int r = u >> 5, s = u & 31;
        const int su = (s ^ (r & 15)) * 8;
        *(float4*)&ai_s[r * HID + su] =
            *(const float4*)&Ai[(b * NCITY + i0 + r) * HID + s * 8];
        *(float4*)&aj_s[r * HID + su] =
            *(const float4*)&Aj[(b * NCITY + j0 + r) * HID + s * 8];
    }
    __syncthreads();

    const int tx = tid & 15;
    const int ty = tid >> 4;

    unsigned a00A = 0u, a00B = 0u, a01A = 0u, a01B = 0u;
    unsigned a10A = 0u, a10B = 0u, a11A = 0u, a11B = 0u;

    #pragma unroll 4
    for (int k8 = 0; k8 < 32; ++k8) {
        const int ci = (k8 ^ ty) * 8;
        const int cj = (k8 ^ tx) * 8;
        H8 x0, x1, y0, y1;
        x0.f4 = *(const float4*)&ai_s[ ty       * HID + ci];
        x1.f4 = *(const float4*)&ai_s[(ty + 16) * HID + ci];
        y0.f4 = *(const float4*)&aj_s[ tx       * HID + cj];
        y1.f4 = *(const float4*)&aj_s[(tx + 16) * HID + cj];

        #pragma unroll
        for (int q = 0; q < 4; ++q) {
            const unsigned w = wd2h[k8 * 4 + q];
            const unsigned t00 = pk_max0(pk_add(x0.u[q], y0.u[q]));
            const unsigned t01 = pk_max0(pk_add(x0.u[q], y1.u[q]));
            const unsigned t10 = pk_max0(pk_add(x1.u[q], y0.u[q]));
            const unsigned t11 = pk_max0(pk_add(x1.u[q], y1.u[q]));
            if (q < 2) {
                a00A = pk_fma(t00, w, a00A);
                a01A = pk_fma(t01, w, a01A);
                a10A = pk_fma(t10, w, a10A);
                a11A = pk_fma(t11, w, a11A);
            } else {
                a00B = pk_fma(t00, w, a00B);
                a01B = pk_fma(t01, w, a01B);
                a10B = pk_fma(t10, w, a10B);
                a11B = pk_fma(t11, w, a11B);
            }
        }
    }

    const float bd = bd2[0];
    float accs[2][2];
    accs[0][0] = sum2(a00A) + sum2(a00B);
    accs[0][1] = sum2(a01A) + sum2(a01B);
    accs[1][0] = sum2(a10A) + sum2(a10B);
    accs[1][1] = sum2(a11A) + sum2(a11B);

    #pragma unroll
    for (int ii = 0; ii < 2; ++ii) {
        #pragma unroll
        for (int jj = 0; jj < 2; ++jj) {
            const int gi = i0 + ty + ii * 16;
            const int gj = j0 + tx + jj * 16;
            const float v = 1.f / (1.f + __expf(-(accs[ii][jj] + bd)));
            p[(b * NCITY + gi) * NCITY + gj] = (gi == gj) ? 0.f : v;
        }
    }
}

// ---------------------------------------------------------------------------
extern "C" void kernel_launch(void* const* d_in, const int* in_sizes, int n_in,
                              void* d_out, int out_size, void* d_ws, size_t ws_size,
                              hipStream_t stream)
{
    const float* cities = (const float*)d_in[0];
    const float* We1    = (const float*)d_in[1];
    const float* be1    = (const float*)d_in[2];
    const float* We2    = (const float*)d_in[3];
    const float* be2    = (const float*)d_in[4];
    const float* Wa1    = (const float*)d_in[5];
    const float* ba1    = (const float*)d_in[6];
    const float* wa2    = (const float*)d_in[7];
    const float* ba2    = (const float*)d_in[8];
    const float* Wd1    = (const float*)d_in[9];
    const float* bd1    = (const float*)d_in[10];
    const float* wd2    = (const float*)d_in[11];
    const float* bd2    = (const float*)d_in[12];
    (void)ba2;   // softmax shift-invariant

    float* out_att = (float*)d_out;                 // [4,384]
    float* out_p   = out_att + M_TOT;               // [4,384,384]

    float*    score_part = (float*)d_ws;                      // 2*1536 f32
    unsigned* We2h_u = (unsigned*)(score_part + 2 * M_TOT);   // 16384 u32
    unsigned* Wh_u   = We2h_u + 16384;                        // 49152 u32
    u16*      emb_h  = (u16*)(Wh_u + 49152);                  // 1536*128 u16
    u16*      Ai_u   = emb_h + M_TOT * DIM;                   // 1536*256 u16
    u16*      Aj_u   = Ai_u + M_TOT * HID;                    // 1536*256 u16

    convert_kernel<<<256, 256, 0, stream>>>(We2, Wa1, Wd1, We2h_u, Wh_u);

    emb_kernel<<<256, 256, 0, stream>>>(
        cities, We1, be1, (const u16*)We2h_u, be2, emb_h);

    heads_kernel<<<dim3(6, 24), 256, 0, stream>>>(
        emb_h, (const u16*)Wh_u, ba1, wa2, bd1, score_part, Ai_u, Aj_u);

    pair_sm_kernel<<<dim3(145, BATCH), 256, 0, stream>>>(
        (const __half*)Ai_u, (const __half*)Aj_u, wd2, bd2,
        score_part, out_att, out_p);
}

// Round 16
// 33.284 us; speedup vs baseline: 2.3938x; 1.1912x over previous
//
#include <hip/hip_runtime.h>
#include <hip/hip_fp16.h>

#define NCITY 384
#define BATCH 4
#define DIM   128
#define HID   256
#define M_TOT (BATCH * NCITY)   // 1536
#define TR    3                 // rows per block -> 512 blocks = 2 blocks/CU

// ---------------------------------------------------------------------------
// K1: streaming encoder (R11 structure, TR=3 for 2 blocks/CU TLP).
// Weights stream global->registers; LDS only for h1/emb + reduce scratch
// (~15.2 KB/block -> 2 blocks co-resident per CU hide each other's stalls).
// ---------------------------------------------------------------------------
__device__ __forceinline__ void chunk_stream(
    const float* __restrict__ W,          // [128][256] row-major, global
    const float (*emb_s)[DIM], float* scr, int tid, float outr[TR])
{
    const int c4 = tid & 63;              // 4 output cols: 4*c4
    const int wv = tid >> 6;              // k-split 4: 32 k each
    const int k0 = wv * 32;

    float4 acc[TR];
    #pragma unroll
    for (int rr = 0; rr < TR; ++rr) acc[rr] = make_float4(0.f, 0.f, 0.f, 0.f);

    #pragma unroll 2
    for (int kb = 0; kb < 32; kb += 4) {
        float4 ev[TR];
        #pragma unroll
        for (int rr = 0; rr < TR; ++rr)
            ev[rr] = *(const float4*)&emb_s[rr][k0 + kb];
        #pragma unroll
        for (int kk = 0; kk < 4; ++kk) {
            const float4 w4 = *(const float4*)&W[(k0 + kb + kk) * HID + c4 * 4];
            #pragma unroll
            for (int rr = 0; rr < TR; ++rr) {
                const float e = ((const float*)&ev[rr])[kk];
                acc[rr].x = fmaf(e, w4.x, acc[rr].x);
                acc[rr].y = fmaf(e, w4.y, acc[rr].y);
                acc[rr].z = fmaf(e, w4.z, acc[rr].z);
                acc[rr].w = fmaf(e, w4.w, acc[rr].w);
            }
        }
    }
    __syncthreads();                      // prior scr readers done
    #pragma unroll
    for (int rr = 0; rr < TR; ++rr)
        *(float4*)&scr[(wv * TR + rr) * HID + c4 * 4] = acc[rr];
    __syncthreads();
    #pragma unroll
    for (int rr = 0; rr < TR; ++rr)
        outr[rr] = scr[(0 * TR + rr) * HID + tid] + scr[(1 * TR + rr) * HID + tid]
                 + scr[(2 * TR + rr) * HID + tid] + scr[(3 * TR + rr) * HID + tid];
}

__global__ __launch_bounds__(256, 2) void encoder_stream(
    const float* __restrict__ cities,
    const float* __restrict__ We1, const float* __restrict__ be1,
    const float* __restrict__ We2, const float* __restrict__ be2,
    const float* __restrict__ Wa1, const float* __restrict__ ba1,
    const float* __restrict__ wa2, const float* __restrict__ ba2,
    const float* __restrict__ Wd1, const float* __restrict__ bd1,
    float* __restrict__ score, float* __restrict__ Ai, float* __restrict__ Aj)
{
    __shared__ float h1_s[TR][HID];       // 3 KB
    __shared__ float emb_s[TR][DIM];      // 1.5 KB
    __shared__ float scr[4 * TR * HID];   // 12 KB reduce scratch
    __shared__ float red2[4][TR];

    const int tid = threadIdx.x;
    const int r0  = blockIdx.x * TR;

    // ---- h1 = relu(cities @ We1 + be1); thread owns k = tid ----------------
    {
        const float w0 = We1[tid], w1 = We1[HID + tid], b1v = be1[tid];
        #pragma unroll
        for (int rr = 0; rr < TR; ++rr) {
            const float cxx = cities[(r0 + rr) * 2];
            const float cyy = cities[(r0 + rr) * 2 + 1];
            h1_s[rr][tid] = fmaxf(fmaf(cxx, w0, fmaf(cyy, w1, b1v)), 0.f);
        }
    }
    __syncthreads();

    // ---- emb = h1 @ We2 + be2 (k-split 8, weights streamed from global) ----
    {
        const int d4 = tid & 31;          // 4 cols: 4*d4
        const int k0 = (tid >> 5) * 32;   // 8 k-groups
        float4 acc[TR];
        #pragma unroll
        for (int rr = 0; rr < TR; ++rr) acc[rr] = make_float4(0.f, 0.f, 0.f, 0.f);

        #pragma unroll 2
        for (int kb = 0; kb < 32; kb += 4) {
            float4 hv[TR];
            #pragma unroll
            for (int rr = 0; rr < TR; ++rr)
                hv[rr] = *(const float4*)&h1_s[rr][k0 + kb];
            #pragma unroll
            for (int kk = 0; kk < 4; ++kk) {
                const float4 w4 = *(const float4*)&We2[(k0 + kb + kk) * DIM + d4 * 4];
                #pragma unroll
                for (int rr = 0; rr < TR; ++rr) {
                    const float h = ((const float*)&hv[rr])[kk];
                    acc[rr].x = fmaf(h, w4.x, acc[rr].x);
                    acc[rr].y = fmaf(h, w4.y, acc[rr].y);
                    acc[rr].z = fmaf(h, w4.z, acc[rr].z);
                    acc[rr].w = fmaf(h, w4.w, acc[rr].w);
                }
            }
        }
        #pragma unroll
        for (int rr = 0; rr < TR; ++rr) {
            acc[rr].x += __shfl_xor(acc[rr].x, 32);
            acc[rr].y += __shfl_xor(acc[rr].y, 32);
            acc[rr].z += __shfl_xor(acc[rr].z, 32);
            acc[rr].w += __shfl_xor(acc[rr].w, 32);
        }
        if ((tid & 63) < 32) {
            const int wv = tid >> 6;
            #pragma unroll
            for (int rr = 0; rr < TR; ++rr)
                *(float4*)&scr[(wv * TR + rr) * DIM + d4 * 4] = acc[rr];
        }
        __syncthreads();
        for (int o = tid; o < TR * DIM; o += 256) {
            const int rr = o >> 7, d = o & (DIM - 1);
            emb_s[rr][d] = scr[(0 * TR + rr) * DIM + d] + scr[(1 * TR + rr) * DIM + d]
                         + scr[(2 * TR + rr) * DIM + d] + scr[(3 * TR + rr) * DIM + d]
                         + be2[d];
        }
        __syncthreads();
    }

    float o6[TR];

    // ---- Wa1 -> attention scores -------------------------------------------
    chunk_stream(Wa1, emb_s, scr, tid, o6);
    {
        const float ba1v = ba1[tid], wa2v = wa2[tid];
        const int wv = tid >> 6;
        #pragma unroll
        for (int rr = 0; rr < TR; ++rr) {
            float v = fmaxf(o6[rr] + ba1v, 0.f) * wa2v;
            #pragma unroll
            for (int off = 32; off > 0; off >>= 1)
                v += __shfl_down(v, off);
            if ((tid & 63) == 0) red2[wv][rr] = v;
        }
        __syncthreads();
        if (tid < TR)
            score[r0 + tid] = red2[0][tid] + red2[1][tid] + red2[2][tid] + red2[3][tid];
        // ba2 dropped: softmax is shift-invariant
    }

    // ---- Wd1 rows 0..127 -> Ai ---------------------------------------------
    chunk_stream(Wd1, emb_s, scr, tid, o6);
    {
        const float bd1v = bd1[tid];
        #pragma unroll
        for (int rr = 0; rr < TR; ++rr)
            Ai[(r0 + rr) * HID + tid] = o6[rr] + bd1v;
    }

    // ---- Wd1 rows 128..255 -> Aj -------------------------------------------
    chunk_stream(Wd1 + DIM * HID, emb_s, scr, tid, o6);
    #pragma unroll
    for (int rr = 0; rr < TR; ++rr)
        Aj[(r0 + rr) * HID + tid] = o6[rr];
    (void)ba2;
}

// ---------------------------------------------------------------------------
// Packed f16 helpers (raw VOP3P; ROCm header __hmax2 broken on gfx950).
// ---------------------------------------------------------------------------
__device__ __forceinline__ unsigned pk_add(unsigned a, unsigned b) {
    unsigned r; asm("v_pk_add_f16 %0, %1, %2" : "=v"(r) : "v"(a), "v"(b)); return r;
}
__device__ __forceinline__ unsigned pk_max0(unsigned a) {
    unsigned r; asm("v_pk_max_f16 %0, %1, %2" : "=v"(r) : "v"(a), "v"(0u)); return r;
}
__device__ __forceinline__ unsigned pk_fma(unsigned a, unsigned b, unsigned c) {
    unsigned r; asm("v_pk_fma_f16 %0, %1, %2, %3" : "=v"(r) : "v"(a), "v"(b), "v"(c)); return r;
}
__device__ __forceinline__ unsigned pack2(float a, float b) {
    union { __half2 h2; unsigned u; } c;
    c.h2 = __float22half2_rn(make_float2(a, b));
    return c.u;
}
__device__ __forceinline__ float sum2(unsigned u) {
    union { unsigned u; __half2 h2; } c; c.u = u;
    return __low2float(c.h2) + __high2float(c.h2);
}
union H8 { float4 f4; unsigned u[4]; };

// ---------------------------------------------------------------------------
// K2: pairwise decoder in packed f16 + fused softmax (verbatim R11 — proven).
// ---------------------------------------------------------------------------
__global__ __launch_bounds__(256) void pair_sm_kernel(
    const float* __restrict__ Ai, const float* __restrict__ Aj,
    const float* __restrict__ wd2, const float* __restrict__ bd2,
    const float* __restrict__ score, float* __restrict__ att,
    float* __restrict__ p)
{
    const int tid = threadIdx.x;
    const int b   = blockIdx.y;

    if (blockIdx.x == 144) {     // ---- softmax block for batch b ------------
        __shared__ float red[8];
        const int t = tid;
        const float v0 = score[b * NCITY + t];
        const bool  h2v = (t < NCITY - 256);
        const float v1 = h2v ? score[b * NCITY + 256 + t] : -3.4e38f;
        float m = fmaxf(v0, v1);
        #pragma unroll
        for (int off = 32; off > 0; off >>= 1)
            m = fmaxf(m, __shfl_down(m, off));
        if ((t & 63) == 0) red[t >> 6] = m;
        __syncthreads();
        m = fmaxf(fmaxf(red[0], red[1]), fmaxf(red[2], red[3]));
        const float e0 = __expf(v0 - m);
        const float e1 = h2v ? __expf(v1 - m) : 0.f;
        float s = e0 + e1;
        #pragma unroll
        for (int off = 32; off > 0; off >>= 1)
            s += __shfl_down(s, off);
        if ((t & 63) == 0) red[4 + (t >> 6)] = s;
        __syncthreads();
        s = red[4] + red[5] + red[6] + red[7];
        att[b * NCITY + t] = e0 / s;
        if (h2v) att[b * NCITY + 256 + t] = e1 / s;
        return;
    }

    // ---- pair tile ---------------------------------------------------------
    __shared__ __half ai_s[32 * HID];    // 16 KB
    __shared__ __half aj_s[32 * HID];    // 16 KB
    __shared__ unsigned wd2h[HID / 2];   // 512 B

    const int i0 = (blockIdx.x / 12) * 32;
    const int j0 = (blockIdx.x % 12) * 32;

    if (tid < HID / 2) {
        const float2 w2 = *(const float2*)&wd2[tid * 2];
        wd2h[tid] = pack2(w2.x, w2.y);
    }

    for (int u = tid; u < 32 * 32; u += 256) {
        const int r = u >> 5, s = u & 31;
        const int su = (s ^ (r & 15)) * 8;
        {
            const int g = (b * NCITY + i0 + r) * HID + s * 8;
            const float4 f0 = *(const float4*)&Ai[g];
            const float4 f1 = *(const float4*)&Ai[g + 4];
            H8 pk;
            pk.u[0] = pack2(f0.x, f0.y);
            pk.u[1] = pack2(f0.z, f0.w);
            pk.u[2] = pack2(f1.x, f1.y);
            pk.u[3] = pack2(f1.z, f1.w);
            *(float4*)&ai_s[r * HID + su] = pk.f4;
        }
        {
            const int g = (b * NCITY + j0 + r) * HID + s * 8;
            const float4 f0 = *(const float4*)&Aj[g];
            const float4 f1 = *(const float4*)&Aj[g + 4];
            H8 pk;
            pk.u[0] = pack2(f0.x, f0.y);
            pk.u[1] = pack2(f0.z, f0.w);
            pk.u[2] = pack2(f1.x, f1.y);
            pk.u[3] = pack2(f1.z, f1.w);
            *(float4*)&aj_s[r * HID + su] = pk.f4;
        }
    }
    __syncthreads();

    const int tx = tid & 15;
    const int ty = tid >> 4;

    unsigned a00A = 0u, a00B = 0u, a01A = 0u, a01B = 0u;
    unsigned a10A = 0u, a10B = 0u, a11A = 0u, a11B = 0u;

    #pragma unroll 4
    for (int k8 = 0; k8 < 32; ++k8) {
        const int ci = (k8 ^ ty) * 8;
        const int cj = (k8 ^ tx) * 8;
        H8 x0, x1, y0, y1;
        x0.f4 = *(const float4*)&ai_s[ ty       * HID + ci];
        x1.f4 = *(const float4*)&ai_s[(ty + 16) * HID + ci];
        y0.f4 = *(const float4*)&aj_s[ tx       * HID + cj];
        y1.f4 = *(const float4*)&aj_s[(tx + 16) * HID + cj];

        #pragma unroll
        for (int q = 0; q < 4; ++q) {
            const unsigned w = wd2h[k8 * 4 + q];
            const unsigned t00 = pk_max0(pk_add(x0.u[q], y0.u[q]));
            const unsigned t01 = pk_max0(pk_add(x0.u[q], y1.u[q]));
            const unsigned t10 = pk_max0(pk_add(x1.u[q], y0.u[q]));
            const unsigned t11 = pk_max0(pk_add(x1.u[q], y1.u[q]));
            if (q < 2) {
                a00A = pk_fma(t00, w, a00A);
                a01A = pk_fma(t01, w, a01A);
                a10A = pk_fma(t10, w, a10A);
                a11A = pk_fma(t11, w, a11A);
            } else {
                a00B = pk_fma(t00, w, a00B);
                a01B = pk_fma(t01, w, a01B);
                a10B = pk_fma(t10, w, a10B);
                a11B = pk_fma(t11, w, a11B);
            }
        }
    }

    const float bd = bd2[0];
    float accs[2][2];
    accs[0][0] = sum2(a00A) + sum2(a00B);
    accs[0][1] = sum2(a01A) + sum2(a01B);
    accs[1][0] = sum2(a10A) + sum2(a10B);
    accs[1][1] = sum2(a11A) + sum2(a11B);

    #pragma unroll
    for (int ii = 0; ii < 2; ++ii) {
        #pragma unroll
        for (int jj = 0; jj < 2; ++jj) {
            const int gi = i0 + ty + ii * 16;
            const int gj = j0 + tx + jj * 16;
            const float v = 1.f / (1.f + __expf(-(accs[ii][jj] + bd)));
            p[(b * NCITY + gi) * NCITY + gj] = (gi == gj) ? 0.f : v;
        }
    }
}

// ---------------------------------------------------------------------------
extern "C" void kernel_launch(void* const* d_in, const int* in_sizes, int n_in,
                              void* d_out, int out_size, void* d_ws, size_t ws_size,
                              hipStream_t stream)
{
    const float* cities = (const float*)d_in[0];
    const float* We1    = (const float*)d_in[1];
    const float* be1    = (const float*)d_in[2];
    const float* We2    = (const float*)d_in[3];
    const float* be2    = (const float*)d_in[4];
    const float* Wa1    = (const float*)d_in[5];
    const float* ba1    = (const float*)d_in[6];
    const float* wa2    = (const float*)d_in[7];
    const float* ba2    = (const float*)d_in[8];
    const float* Wd1    = (const float*)d_in[9];
    const float* bd1    = (const float*)d_in[10];
    const float* wd2    = (const float*)d_in[11];
    const float* bd2    = (const float*)d_in[12];

    float* out_att = (float*)d_out;                 // [4,384]
    float* out_p   = out_att + M_TOT;               // [4,384,384]

    float* score = (float*)d_ws;                    // 1536
    float* Ai    = score + M_TOT;                   // 1536*256
    float* Aj    = Ai + M_TOT * HID;                // 1536*256

    encoder_stream<<<M_TOT / TR, 256, 0, stream>>>(
        cities, We1, be1, We2, be2, Wa1, ba1, wa2, ba2, Wd1, bd1,
        score, Ai, Aj);

    pair_sm_kernel<<<dim3(145, BATCH), 256, 0, stream>>>(
        Ai, Aj, wd2, bd2, score, out_att, out_p);
}